// Round 6
// baseline (1380.123 us; speedup 1.0000x reference)
//
#include <hip/hip_runtime.h>
#include <cstdint>

#define KU 256
#define NBASK 64
#define MBS 20
#define BITEMS 1280
#define HD 256
#define G3 768
#define TT 64

typedef short v8s __attribute__((ext_vector_type(8)));
typedef float v4f __attribute__((ext_vector_type(4)));

__device__ __forceinline__ unsigned short f2b(float f){
  uint32_t u = __float_as_uint(f);
  u += 0x7FFFu + ((u >> 16) & 1u);
  return (unsigned short)(u >> 16);
}
__device__ __forceinline__ float b2f(unsigned short s){
  return __uint_as_float(((uint32_t)s) << 16);
}

// ---------------- weight conversion: fp32 -> bf16 hi + residual lo ---------
__global__ __launch_bounds__(1024) void k_convert(
    const float* __restrict__ wih, const float* __restrict__ whh,
    unsigned short* __restrict__ wih1hi, unsigned short* __restrict__ wih1lo,
    unsigned short* __restrict__ wih2hi, unsigned short* __restrict__ wih2lo,
    unsigned short* __restrict__ whh1hi, unsigned short* __restrict__ whh1lo,
    unsigned short* __restrict__ whh2hi, unsigned short* __restrict__ whh2lo)
{
  int idx = blockIdx.x * 1024 + threadIdx.x;     // 0..196607
  int which = blockIdx.y;
  float v;
  if (which == 0)      v = wih[idx];
  else if (which == 1) v = wih[196608 + idx];
  else if (which == 2) v = whh[idx];
  else                 v = whh[196608 + idx];
  unsigned short hi = f2b(v);
  unsigned short lo = f2b(v - b2f(hi));
  if (which == 0)      { wih1hi[idx] = hi; wih1lo[idx] = lo; }
  else if (which == 1) { wih2hi[idx] = hi; wih2lo[idx] = lo; }
  else if (which == 2) { whh1hi[idx] = hi; whh1lo[idx] = lo; }
  else                 { whh2hi[idx] = hi; whh2lo[idx] = lo; }
}

// ---------------- per-user basket ordering (stable: valid first) -----------
__global__ __launch_bounds__(64) void k_order(
    const float* __restrict__ prob, const int* __restrict__ seq,
    int* __restrict__ order, int* __restrict__ lengths)
{
  int k = blockIdx.x, j = threadIdx.x;           // j = basket
  int base = k * BITEMS + j * MBS;
  float mx = 0.f;
  #pragma unroll
  for (int m = 0; m < MBS; m++) {
    int it = seq[base + m];
    float p = (it >= 0) ? prob[base + m] : 0.f;
    mx = fmaxf(mx, p);
  }
  bool valid = mx > 0.f;
  unsigned long long bal = __ballot(valid);
  int len = __popcll(bal);
  unsigned long long below = bal & ((1ull << j) - 1ull);
  int pos = valid ? __popcll(below) : (len + (j - __popcll(below)));
  order[k * NBASK + j] = pos;
  if (j == 0) lengths[k] = (len > 0) ? len : 1;
}

// ---------------- basket pooling -> ordered x (bf16 hi+lo) -----------------
__global__ __launch_bounds__(256) void k_basket(
    const float* __restrict__ prob, const int* __restrict__ seq,
    const float* __restrict__ table, const int* __restrict__ order,
    unsigned short* __restrict__ xbhi, unsigned short* __restrict__ xblo)
{
  int j = blockIdx.x, k = blockIdx.y;
  int h = threadIdx.x;
  int base = k * BITEMS + j * MBS;
  float acc = 0.f, sp = 0.f;
  #pragma unroll
  for (int m = 0; m < MBS; m++) {
    int it = seq[base + m];
    if (it >= 0) {
      float p = prob[base + m];
      sp += p;
      acc += p * table[(size_t)(it + 1) * HD + h];
    }
  }
  float val = acc / (sp + 1e-10f);
  int dest = order[k * NBASK + j];
  unsigned short hi = f2b(val);
  size_t o = ((size_t)k * NBASK + dest) * HD + h;
  xbhi[o] = hi;
  xblo[o] = f2b(val - b2f(hi));
}

// ---------------- 3-product split-bf16 GEMM: Y = X @ W^T + bias ------------
// X [16384][256] (hi,lo), W [768][256] (hi,lo), Y [16384][768] fp32
__global__ __launch_bounds__(256) void k_gemm3(
    const unsigned short* __restrict__ Xhi, const unsigned short* __restrict__ Xlo,
    const unsigned short* __restrict__ Whi, const unsigned short* __restrict__ Wlo,
    const float* __restrict__ bias, float* __restrict__ Y)
{
  int nblk = blockIdx.x;              // 0..11
  int mblk = blockIdx.y;              // 0..255
  int wv = threadIdx.x >> 6;
  int l = threadIdx.x & 63;
  int r = l & 15, g = l >> 4;
  int mbase = mblk * 64 + wv * 16;
  int nbase = nblk * 64;
  v4f acc[4];
  #pragma unroll
  for (int c = 0; c < 4; c++) {
    float bn = bias[nbase + c * 16 + r];
    acc[c] = (v4f){bn, bn, bn, bn};
  }
  const unsigned short* xh = Xhi + (size_t)(mbase + r) * HD;
  const unsigned short* xl = Xlo + (size_t)(mbase + r) * HD;
  #pragma unroll
  for (int k0 = 0; k0 < HD; k0 += 32) {
    v8s ahi = *(const v8s*)(xh + k0 + g * 8);
    v8s alo = *(const v8s*)(xl + k0 + g * 8);
    #pragma unroll
    for (int c = 0; c < 4; c++) {
      size_t wo = (size_t)(nbase + c * 16 + r) * HD + k0 + g * 8;
      v8s bhi = *(const v8s*)(Whi + wo);
      v8s blo = *(const v8s*)(Wlo + wo);
      acc[c] = __builtin_amdgcn_mfma_f32_16x16x32_bf16(ahi, bhi, acc[c], 0, 0, 0);
      acc[c] = __builtin_amdgcn_mfma_f32_16x16x32_bf16(alo, bhi, acc[c], 0, 0, 0);
      acc[c] = __builtin_amdgcn_mfma_f32_16x16x32_bf16(ahi, blo, acc[c], 0, 0, 0);
    }
  }
  #pragma unroll
  for (int c = 0; c < 4; c++) {
    int n = nbase + c * 16 + r;
    int mrow = mbase + g * 4;
    #pragma unroll
    for (int i = 0; i < 4; i++)
      Y[(size_t)(mrow + i) * G3 + n] = acc[c][i];
  }
}

// ---------------- single-layer GRU recurrence ------------------------------
// 16 blocks x 1024 threads (16 waves, 1 block/CU, 4 waves/SIMD, 128-reg cap).
// Budget-fit by construction: whi[3][4] persistent = 48 VGPRs; kk>=4 weight
// slices streamed from L2 (depth-1 pipeline); n-gate lo weights staged ONCE
// into LDS (swizzled); gates computed fully in-register from the MFMA
// C-fragment (lane holds r/z/n for the same (user,j)); h_old in fp32 regs.
// LDS: h hi/lo (16KB) + nlo (128KB) = 144KB. No bufA, no gi staging.
// MODE 0: publish h(t) sequence (hi+lo). MODE 1: out at t==len-1.
template<int MODE>
__global__ __launch_bounds__(1024) void k_recur(
    const unsigned short* __restrict__ whi_g, const unsigned short* __restrict__ wlo_g,
    const float* __restrict__ gi, const float* __restrict__ bhh,
    const int* __restrict__ lengths,
    unsigned short* __restrict__ hseq_hi, unsigned short* __restrict__ hseq_lo,
    float* __restrict__ out)
{
  __shared__ unsigned short h_hi[16][256], h_lo[16][256];
  __shared__ unsigned short nlo_s[256 * 256];    // n-gate w-lo, swizzled (128 KB)
  int tid = threadIdx.x;
  int l = tid & 63, r = l & 15, g = l >> 4;
  int swv = __builtin_amdgcn_readfirstlane(tid >> 6);   // wave id (SGPR)
  int ub = blockIdx.x * 16;
  int j = swv * 16 + r;                          // this lane's output column

  for (int idx = tid; idx < 4096; idx += 1024) {
    ((unsigned short*)h_hi)[idx] = 0;
    ((unsigned short*)h_lo)[idx] = 0;
  }
  // stage n-gate lo weights into LDS with the MFMA-read swizzle
  const unsigned short* wlo_n = wlo_g + 2 * 65536;
  for (int idx = tid; idx < 65536; idx += 1024) {
    int row = idx >> 8, col = idx & 255;
    int slot = (col >> 3) ^ (row & 7);           // (kk*4+g) ^ (row&7)
    nlo_s[row * 256 + slot * 8 + (col & 7)] = wlo_n[idx];
  }
  // persistent whh-hi fragments, first 4 k-slices only (48 VGPRs)
  v8s whi[3][4];
  int voff = r * 256 + g * 8;
  const unsigned short* wst = whi_g + swv * 4096 + voff;
  #pragma unroll
  for (int tt = 0; tt < 3; tt++)
    #pragma unroll
    for (int kk = 0; kk < 4; kk++)
      whi[tt][kk] = *(const v8s*)&wst[tt * 65536 + kk * 32];
  // per-lane biases and lengths
  float b_r = bhh[j], b_z = bhh[256 + j], b_n = bhh[512 + j];
  int lenr[4];
  if (MODE == 1) {
    #pragma unroll
    for (int i = 0; i < 4; i++) lenr[i] = lengths[ub + g * 4 + i];
  }
  float hold[4] = {0.f, 0.f, 0.f, 0.f};
  __syncthreads();

  for (int t = 0; t < TT; t++) {
    // ---- prefetch gi(t) for the gates (consumed after the MFMA phase) ----
    float gir[4], giz[4], gin[4];
    #pragma unroll
    for (int i = 0; i < 4; i++) {
      const float* gp = gi + ((size_t)(ub + g * 4 + i) * TT + t) * G3 + j;
      gir[i] = gp[0]; giz[i] = gp[256]; gin[i] = gp[512];
    }
    // ---- MM: gh rows {j, 256+j, 512+j}; A = h of 16 users ----
    v4f a0 = {0.f,0.f,0.f,0.f}, a1 = {0.f,0.f,0.f,0.f}, a2 = {0.f,0.f,0.f,0.f};
    #pragma unroll
    for (int kk = 0; kk < 4; kk++) {             // register-resident half
      int slotA = ((kk * 4 + g) ^ (r & 7)) * 8;
      v8s ahi = *(const v8s*)&h_hi[r][slotA];
      v8s alo = *(const v8s*)&h_lo[r][slotA];
      v8s nl  = *(const v8s*)&nlo_s[j * 256 + slotA];
      a0 = __builtin_amdgcn_mfma_f32_16x16x32_bf16(ahi, whi[0][kk], a0, 0, 0, 0);
      a0 = __builtin_amdgcn_mfma_f32_16x16x32_bf16(alo, whi[0][kk], a0, 0, 0, 0);
      a1 = __builtin_amdgcn_mfma_f32_16x16x32_bf16(ahi, whi[1][kk], a1, 0, 0, 0);
      a1 = __builtin_amdgcn_mfma_f32_16x16x32_bf16(alo, whi[1][kk], a1, 0, 0, 0);
      a2 = __builtin_amdgcn_mfma_f32_16x16x32_bf16(ahi, whi[2][kk], a2, 0, 0, 0);
      a2 = __builtin_amdgcn_mfma_f32_16x16x32_bf16(alo, whi[2][kk], a2, 0, 0, 0);
      a2 = __builtin_amdgcn_mfma_f32_16x16x32_bf16(ahi, nl,         a2, 0, 0, 0);
    }
    v8s cw0 = *(const v8s*)&wst[0 * 65536 + 4 * 32];   // streamed half, depth-1
    v8s cw1 = *(const v8s*)&wst[1 * 65536 + 4 * 32];
    v8s cw2 = *(const v8s*)&wst[2 * 65536 + 4 * 32];
    #pragma unroll
    for (int kk = 4; kk < 8; kk++) {
      int slotA = ((kk * 4 + g) ^ (r & 7)) * 8;
      v8s ahi = *(const v8s*)&h_hi[r][slotA];
      v8s alo = *(const v8s*)&h_lo[r][slotA];
      v8s nl  = *(const v8s*)&nlo_s[j * 256 + slotA];
      v8s u0 = cw0, u1 = cw1, u2 = cw2;
      if (kk < 7) {
        cw0 = *(const v8s*)&wst[0 * 65536 + (kk + 1) * 32];
        cw1 = *(const v8s*)&wst[1 * 65536 + (kk + 1) * 32];
        cw2 = *(const v8s*)&wst[2 * 65536 + (kk + 1) * 32];
      }
      a0 = __builtin_amdgcn_mfma_f32_16x16x32_bf16(ahi, u0, a0, 0, 0, 0);
      a0 = __builtin_amdgcn_mfma_f32_16x16x32_bf16(alo, u0, a0, 0, 0, 0);
      a1 = __builtin_amdgcn_mfma_f32_16x16x32_bf16(ahi, u1, a1, 0, 0, 0);
      a1 = __builtin_amdgcn_mfma_f32_16x16x32_bf16(alo, u1, a1, 0, 0, 0);
      a2 = __builtin_amdgcn_mfma_f32_16x16x32_bf16(ahi, u2, a2, 0, 0, 0);
      a2 = __builtin_amdgcn_mfma_f32_16x16x32_bf16(alo, u2, a2, 0, 0, 0);
      a2 = __builtin_amdgcn_mfma_f32_16x16x32_bf16(ahi, nl, a2, 0, 0, 0);
    }
    __syncthreads();                 // all waves done reading h(t-1)
    // ---- gates in-register: lane element i = (user g*4+i, column j) ----
    #pragma unroll
    for (int i = 0; i < 4; i++) {
      float hr = a0[i] + b_r, hz = a1[i] + b_z, hn = a2[i] + b_n;
      float rr = 1.f / (1.f + __expf(-(gir[i] + hr)));
      float zz = 1.f / (1.f + __expf(-(giz[i] + hz)));
      float e  = __expf(2.f * (gin[i] + rr * hn));
      float nn = 1.f - 2.f / (e + 1.f);
      float hnew = (1.f - zz) * nn + zz * hold[i];
      hold[i] = hnew;
      unsigned short h_  = f2b(hnew);
      unsigned short lo_ = f2b(hnew - b2f(h_));
      int u = g * 4 + i;
      int pos = (((j >> 3) ^ (u & 7)) << 3) + (j & 7);   // swizzled h slot
      h_hi[u][pos] = h_;
      h_lo[u][pos] = lo_;
      if (MODE == 0) {
        size_t o = ((size_t)(ub + u) * TT + t) * HD + j;
        hseq_hi[o] = h_;
        hseq_lo[o] = lo_;
      } else {
        if (t == lenr[i] - 1)
          out[(size_t)(ub + u) * HD + j] = hnew;
      }
    }
    __syncthreads();                 // h(t) visible to all waves
  }
}

extern "C" void kernel_launch(void* const* d_in, const int* in_sizes, int n_in,
                              void* d_out, int out_size, void* d_ws, size_t ws_size,
                              hipStream_t stream) {
  const float* prob  = (const float*)d_in[0];
  const int*   seq   = (const int*)d_in[1];
  // d_in[2] = uid (unused by the reference output)
  const float* table = (const float*)d_in[3];
  const float* wih   = (const float*)d_in[4];
  const float* whh   = (const float*)d_in[5];
  const float* bih   = (const float*)d_in[6];
  const float* bhh   = (const float*)d_in[7];
  float* out = (float*)d_out;

  char* ws = (char*)d_ws;
  float* gi            = (float*)ws;                          // 50,331,648 B (gi1, reused as gi2)
  unsigned short* xbhi = (unsigned short*)(ws + 50331648);    // 8 MB
  unsigned short* xblo = (unsigned short*)(ws + 58720256);    // 8 MB
  unsigned short* h1hi = xbhi;   // overlay: xb dead after gemm1, h1 born in recur1
  unsigned short* h1lo = xblo;
  char* wsw = ws + 67108864;
  const size_t WSZ = 393216;                                  // 768*256*2 B
  unsigned short* wih1hi = (unsigned short*)(wsw + 0 * WSZ);
  unsigned short* wih1lo = (unsigned short*)(wsw + 1 * WSZ);
  unsigned short* wih2hi = (unsigned short*)(wsw + 2 * WSZ);
  unsigned short* wih2lo = (unsigned short*)(wsw + 3 * WSZ);
  unsigned short* whh1hi = (unsigned short*)(wsw + 4 * WSZ);
  unsigned short* whh1lo = (unsigned short*)(wsw + 5 * WSZ);
  unsigned short* whh2hi = (unsigned short*)(wsw + 6 * WSZ);
  unsigned short* whh2lo = (unsigned short*)(wsw + 7 * WSZ);
  int* order   = (int*)(wsw + 8 * WSZ);
  int* lengths = order + KU * NBASK;

  k_convert<<<dim3(192, 4), 1024, 0, stream>>>(wih, whh,
      wih1hi, wih1lo, wih2hi, wih2lo, whh1hi, whh1lo, whh2hi, whh2lo);
  k_order<<<dim3(KU), 64, 0, stream>>>(prob, seq, order, lengths);
  k_basket<<<dim3(NBASK, KU), 256, 0, stream>>>(prob, seq, table, order, xbhi, xblo);
  // gi1 = x @ wih1^T + bih1
  k_gemm3<<<dim3(12, 256), 256, 0, stream>>>(xbhi, xblo, wih1hi, wih1lo, bih, gi);
  // layer-1 recurrence -> h1 sequence
  k_recur<0><<<dim3(16), 1024, 0, stream>>>(whh1hi, whh1lo, gi, bhh,
                                            nullptr, h1hi, h1lo, nullptr);
  // gi2 = h1 @ wih2^T + bih2  (overwrites gi buffer)
  k_gemm3<<<dim3(12, 256), 256, 0, stream>>>(h1hi, h1lo, wih2hi, wih2lo, bih + G3, gi);
  // layer-2 recurrence -> output at t == len-1
  k_recur<1><<<dim3(16), 1024, 0, stream>>>(whh2hi, whh2lo, gi, bhh + G3,
                                            lengths, nullptr, nullptr, out);
}

// Round 7
// 1353.687 us; speedup vs baseline: 1.0195x; 1.0195x over previous
//
#include <hip/hip_runtime.h>
#include <cstdint>

#define KU 256
#define NBASK 64
#define MBS 20
#define BITEMS 1280
#define HD 256
#define G3 768
#define TT 64

typedef short v8s __attribute__((ext_vector_type(8)));
typedef float v4f __attribute__((ext_vector_type(4)));

__device__ __forceinline__ unsigned short f2b(float f){
  uint32_t u = __float_as_uint(f);
  u += 0x7FFFu + ((u >> 16) & 1u);
  return (unsigned short)(u >> 16);
}
__device__ __forceinline__ float b2f(unsigned short s){
  return __uint_as_float(((uint32_t)s) << 16);
}

// ---------------- weight conversion: fp32 -> bf16 hi + residual lo ---------
__global__ __launch_bounds__(1024) void k_convert(
    const float* __restrict__ wih, const float* __restrict__ whh,
    unsigned short* __restrict__ wih1hi, unsigned short* __restrict__ wih1lo,
    unsigned short* __restrict__ wih2hi, unsigned short* __restrict__ wih2lo,
    unsigned short* __restrict__ whh1hi, unsigned short* __restrict__ whh1lo,
    unsigned short* __restrict__ whh2hi, unsigned short* __restrict__ whh2lo)
{
  int idx = blockIdx.x * 1024 + threadIdx.x;     // 0..196607
  int which = blockIdx.y;
  float v;
  if (which == 0)      v = wih[idx];
  else if (which == 1) v = wih[196608 + idx];
  else if (which == 2) v = whh[idx];
  else                 v = whh[196608 + idx];
  unsigned short hi = f2b(v);
  unsigned short lo = f2b(v - b2f(hi));
  if (which == 0)      { wih1hi[idx] = hi; wih1lo[idx] = lo; }
  else if (which == 1) { wih2hi[idx] = hi; wih2lo[idx] = lo; }
  else if (which == 2) { whh1hi[idx] = hi; whh1lo[idx] = lo; }
  else                 { whh2hi[idx] = hi; whh2lo[idx] = lo; }
}

// ---------------- per-user basket ordering (stable: valid first) -----------
__global__ __launch_bounds__(64) void k_order(
    const float* __restrict__ prob, const int* __restrict__ seq,
    int* __restrict__ order, int* __restrict__ lengths)
{
  int k = blockIdx.x, j = threadIdx.x;           // j = basket
  int base = k * BITEMS + j * MBS;
  float mx = 0.f;
  #pragma unroll
  for (int m = 0; m < MBS; m++) {
    int it = seq[base + m];
    float p = (it >= 0) ? prob[base + m] : 0.f;
    mx = fmaxf(mx, p);
  }
  bool valid = mx > 0.f;
  unsigned long long bal = __ballot(valid);
  int len = __popcll(bal);
  unsigned long long below = bal & ((1ull << j) - 1ull);
  int pos = valid ? __popcll(below) : (len + (j - __popcll(below)));
  order[k * NBASK + j] = pos;
  if (j == 0) lengths[k] = (len > 0) ? len : 1;
}

// ---------------- basket pooling -> ordered x (bf16 hi+lo) -----------------
__global__ __launch_bounds__(256) void k_basket(
    const float* __restrict__ prob, const int* __restrict__ seq,
    const float* __restrict__ table, const int* __restrict__ order,
    unsigned short* __restrict__ xbhi, unsigned short* __restrict__ xblo)
{
  int j = blockIdx.x, k = blockIdx.y;
  int h = threadIdx.x;
  int base = k * BITEMS + j * MBS;
  float acc = 0.f, sp = 0.f;
  #pragma unroll
  for (int m = 0; m < MBS; m++) {
    int it = seq[base + m];
    if (it >= 0) {
      float p = prob[base + m];
      sp += p;
      acc += p * table[(size_t)(it + 1) * HD + h];
    }
  }
  float val = acc / (sp + 1e-10f);
  int dest = order[k * NBASK + j];
  unsigned short hi = f2b(val);
  size_t o = ((size_t)k * NBASK + dest) * HD + h;
  xbhi[o] = hi;
  xblo[o] = f2b(val - b2f(hi));
}

// ---------------- 3-product split-bf16 GEMM: Y = X @ W^T + bias ------------
// X [16384][256] (hi,lo), W [768][256] (hi,lo), Y [16384][768] fp32
__global__ __launch_bounds__(256) void k_gemm3(
    const unsigned short* __restrict__ Xhi, const unsigned short* __restrict__ Xlo,
    const unsigned short* __restrict__ Whi, const unsigned short* __restrict__ Wlo,
    const float* __restrict__ bias, float* __restrict__ Y)
{
  int nblk = blockIdx.x;              // 0..11
  int mblk = blockIdx.y;              // 0..255
  int wv = threadIdx.x >> 6;
  int l = threadIdx.x & 63;
  int r = l & 15, g = l >> 4;
  int mbase = mblk * 64 + wv * 16;
  int nbase = nblk * 64;
  v4f acc[4];
  #pragma unroll
  for (int c = 0; c < 4; c++) {
    float bn = bias[nbase + c * 16 + r];
    acc[c] = (v4f){bn, bn, bn, bn};
  }
  const unsigned short* xh = Xhi + (size_t)(mbase + r) * HD;
  const unsigned short* xl = Xlo + (size_t)(mbase + r) * HD;
  #pragma unroll
  for (int k0 = 0; k0 < HD; k0 += 32) {
    v8s ahi = *(const v8s*)(xh + k0 + g * 8);
    v8s alo = *(const v8s*)(xl + k0 + g * 8);
    #pragma unroll
    for (int c = 0; c < 4; c++) {
      size_t wo = (size_t)(nbase + c * 16 + r) * HD + k0 + g * 8;
      v8s bhi = *(const v8s*)(Whi + wo);
      v8s blo = *(const v8s*)(Wlo + wo);
      acc[c] = __builtin_amdgcn_mfma_f32_16x16x32_bf16(ahi, bhi, acc[c], 0, 0, 0);
      acc[c] = __builtin_amdgcn_mfma_f32_16x16x32_bf16(alo, bhi, acc[c], 0, 0, 0);
      acc[c] = __builtin_amdgcn_mfma_f32_16x16x32_bf16(ahi, blo, acc[c], 0, 0, 0);
    }
  }
  #pragma unroll
  for (int c = 0; c < 4; c++) {
    int n = nbase + c * 16 + r;
    int mrow = mbase + g * 4;
    #pragma unroll
    for (int i = 0; i < 4; i++)
      Y[(size_t)(mrow + i) * G3 + n] = acc[c][i];
  }
}

// ---------------- single-layer GRU recurrence, streaming-clean -------------
// 16 blocks x 1024 threads (16 waves). ZERO persistent weight registers:
// whh-hi streamed from L2 every step, depth-3 double-buffer (static idx).
// n-gate lo weights in LDS (swizzled); h hi/lo in LDS; gates in-register.
// vmcnt hygiene: all 24 weight loads issue BEFORE the 12 gi (HBM) loads, so
// counted waits on weights never block on HBM; gi drains at the barrier.
// MODE 0: publish h(t) sequence (hi+lo). MODE 1: out at t==len-1.
template<int MODE>
__global__ __launch_bounds__(1024) void k_recur(
    const unsigned short* __restrict__ whi_g, const unsigned short* __restrict__ wlo_g,
    const float* __restrict__ gi, const float* __restrict__ bhh,
    const int* __restrict__ lengths,
    unsigned short* __restrict__ hseq_hi, unsigned short* __restrict__ hseq_lo,
    float* __restrict__ out)
{
  __shared__ unsigned short h_hi[16][256], h_lo[16][256];
  __shared__ unsigned short nlo_s[256 * 256];    // n-gate w-lo, swizzled (128 KB)
  int tid = threadIdx.x;
  int l = tid & 63, r = l & 15, g = l >> 4;
  int swv = __builtin_amdgcn_readfirstlane(tid >> 6);   // wave id (SGPR)
  int ub = blockIdx.x * 16;
  int j = swv * 16 + r;                          // this lane's output column

  for (int idx = tid; idx < 4096; idx += 1024) {
    ((unsigned short*)h_hi)[idx] = 0;
    ((unsigned short*)h_lo)[idx] = 0;
  }
  // stage n-gate lo weights into LDS with the MFMA-read swizzle
  const unsigned short* wlo_n = wlo_g + 2 * 65536;
  for (int idx = tid; idx < 65536; idx += 1024) {
    int row = idx >> 8, col = idx & 255;
    int slot = (col >> 3) ^ (row & 7);           // (kk*4+g) ^ (row&7)
    nlo_s[row * 256 + slot * 8 + (col & 7)] = wlo_n[idx];
  }
  // per-wave weight-stream row pointers (rows j, 256+j, 512+j)
  const unsigned short* w0 = whi_g + (size_t)j * 256 + g * 8;
  const unsigned short* w1 = w0 + 65536;
  const unsigned short* w2 = w0 + 131072;
  // per-lane biases, lengths, gi/hseq pointers
  float b_r = bhh[j], b_z = bhh[256 + j], b_n = bhh[512 + j];
  int lenr[4];
  const float* gp[4];
  unsigned short* hqh[4];
  unsigned short* hql[4];
  #pragma unroll
  for (int i = 0; i < 4; i++) {
    int u = g * 4 + i;
    gp[i] = gi + (size_t)(ub + u) * TT * G3 + j;
    if (MODE == 0) {
      hqh[i] = hseq_hi + (size_t)(ub + u) * TT * HD + j;
      hql[i] = hseq_lo + (size_t)(ub + u) * TT * HD + j;
    } else {
      lenr[i] = lengths[ub + u];
    }
  }
  float hold[4] = {0.f, 0.f, 0.f, 0.f};
  __syncthreads();

  for (int t = 0; t < TT; t++) {
    // ---- prologue: issue depth-3 weight prefetch (9 loads) ----
    v8s cw0[3], cw1[3], cw2[3];
    #pragma unroll
    for (int p = 0; p < 3; p++) {
      cw0[p] = *(const v8s*)(w0 + p * 32);
      cw1[p] = *(const v8s*)(w1 + p * 32);
      cw2[p] = *(const v8s*)(w2 + p * 32);
    }
    v4f a0 = {0.f,0.f,0.f,0.f}, a1 = {0.f,0.f,0.f,0.f}, a2 = {0.f,0.f,0.f,0.f};
    float gir[4], giz[4], gin[4];
    #pragma unroll
    for (int kk = 0; kk < 8; kk++) {
      int buf = kk % 3;                          // static after unroll
      int slotA = ((kk * 4 + g) ^ (r & 7)) * 8;
      v8s ahi = *(const v8s*)&h_hi[r][slotA];
      v8s alo = *(const v8s*)&h_lo[r][slotA];
      v8s nl  = *(const v8s*)&nlo_s[j * 256 + slotA];
      v8s u0 = cw0[buf], u1 = cw1[buf], u2 = cw2[buf];
      if (kk + 3 < 8) {                          // keep issuing the W stream
        cw0[buf] = *(const v8s*)(w0 + (kk + 3) * 32);
        cw1[buf] = *(const v8s*)(w1 + (kk + 3) * 32);
        cw2[buf] = *(const v8s*)(w2 + (kk + 3) * 32);
      }
      if (kk == 4) {                             // all 24 W issued -> now gi
        #pragma unroll
        for (int i = 0; i < 4; i++) {
          gir[i] = gp[i][0];
          giz[i] = gp[i][256];
          gin[i] = gp[i][512];
        }
      }
      a0 = __builtin_amdgcn_mfma_f32_16x16x32_bf16(ahi, u0, a0, 0, 0, 0);
      a0 = __builtin_amdgcn_mfma_f32_16x16x32_bf16(alo, u0, a0, 0, 0, 0);
      a1 = __builtin_amdgcn_mfma_f32_16x16x32_bf16(ahi, u1, a1, 0, 0, 0);
      a1 = __builtin_amdgcn_mfma_f32_16x16x32_bf16(alo, u1, a1, 0, 0, 0);
      a2 = __builtin_amdgcn_mfma_f32_16x16x32_bf16(ahi, u2, a2, 0, 0, 0);
      a2 = __builtin_amdgcn_mfma_f32_16x16x32_bf16(alo, u2, a2, 0, 0, 0);
      a2 = __builtin_amdgcn_mfma_f32_16x16x32_bf16(ahi, nl, a2, 0, 0, 0);
    }
    __syncthreads();                 // all waves done reading h(t-1); gi drained
    // ---- gates in-register: lane element i = (user g*4+i, column j) ----
    #pragma unroll
    for (int i = 0; i < 4; i++) {
      float hr = a0[i] + b_r, hz = a1[i] + b_z, hn = a2[i] + b_n;
      float rr = 1.f / (1.f + __expf(-(gir[i] + hr)));
      float zz = 1.f / (1.f + __expf(-(giz[i] + hz)));
      float e  = __expf(2.f * (gin[i] + rr * hn));
      float nn = 1.f - 2.f / (e + 1.f);
      float hnew = (1.f - zz) * nn + zz * hold[i];
      hold[i] = hnew;
      unsigned short h_  = f2b(hnew);
      unsigned short lo_ = f2b(hnew - b2f(h_));
      int u = g * 4 + i;
      int pos = (((j >> 3) ^ (u & 7)) << 3) + (j & 7);   // swizzled h slot
      h_hi[u][pos] = h_;
      h_lo[u][pos] = lo_;
      if (MODE == 0) {
        hqh[i][0] = h_;
        hql[i][0] = lo_;
        hqh[i] += HD;
        hql[i] += HD;
      } else {
        if (t == lenr[i] - 1)
          out[(size_t)(ub + u) * HD + j] = hnew;
      }
      gp[i] += G3;
    }
    __syncthreads();                 // h(t) visible to all waves
  }
}

extern "C" void kernel_launch(void* const* d_in, const int* in_sizes, int n_in,
                              void* d_out, int out_size, void* d_ws, size_t ws_size,
                              hipStream_t stream) {
  const float* prob  = (const float*)d_in[0];
  const int*   seq   = (const int*)d_in[1];
  // d_in[2] = uid (unused by the reference output)
  const float* table = (const float*)d_in[3];
  const float* wih   = (const float*)d_in[4];
  const float* whh   = (const float*)d_in[5];
  const float* bih   = (const float*)d_in[6];
  const float* bhh   = (const float*)d_in[7];
  float* out = (float*)d_out;

  char* ws = (char*)d_ws;
  float* gi            = (float*)ws;                          // 50,331,648 B (gi1, reused as gi2)
  unsigned short* xbhi = (unsigned short*)(ws + 50331648);    // 8 MB
  unsigned short* xblo = (unsigned short*)(ws + 58720256);    // 8 MB
  unsigned short* h1hi = xbhi;   // overlay: xb dead after gemm1, h1 born in recur1
  unsigned short* h1lo = xblo;
  char* wsw = ws + 67108864;
  const size_t WSZ = 393216;                                  // 768*256*2 B
  unsigned short* wih1hi = (unsigned short*)(wsw + 0 * WSZ);
  unsigned short* wih1lo = (unsigned short*)(wsw + 1 * WSZ);
  unsigned short* wih2hi = (unsigned short*)(wsw + 2 * WSZ);
  unsigned short* wih2lo = (unsigned short*)(wsw + 3 * WSZ);
  unsigned short* whh1hi = (unsigned short*)(wsw + 4 * WSZ);
  unsigned short* whh1lo = (unsigned short*)(wsw + 5 * WSZ);
  unsigned short* whh2hi = (unsigned short*)(wsw + 6 * WSZ);
  unsigned short* whh2lo = (unsigned short*)(wsw + 7 * WSZ);
  int* order   = (int*)(wsw + 8 * WSZ);
  int* lengths = order + KU * NBASK;

  k_convert<<<dim3(192, 4), 1024, 0, stream>>>(wih, whh,
      wih1hi, wih1lo, wih2hi, wih2lo, whh1hi, whh1lo, whh2hi, whh2lo);
  k_order<<<dim3(KU), 64, 0, stream>>>(prob, seq, order, lengths);
  k_basket<<<dim3(NBASK, KU), 256, 0, stream>>>(prob, seq, table, order, xbhi, xblo);
  // gi1 = x @ wih1^T + bih1
  k_gemm3<<<dim3(12, 256), 256, 0, stream>>>(xbhi, xblo, wih1hi, wih1lo, bih, gi);
  // layer-1 recurrence -> h1 sequence
  k_recur<0><<<dim3(16), 1024, 0, stream>>>(whh1hi, whh1lo, gi, bhh,
                                            nullptr, h1hi, h1lo, nullptr);
  // gi2 = h1 @ wih2^T + bih2  (overwrites gi buffer)
  k_gemm3<<<dim3(12, 256), 256, 0, stream>>>(h1hi, h1lo, wih2hi, wih2lo, bih + G3, gi);
  // layer-2 recurrence -> output at t == len-1
  k_recur<1><<<dim3(16), 1024, 0, stream>>>(whh2hi, whh2lo, gi, bhh + G3,
                                            lengths, nullptr, nullptr, out);
}

// Round 8
// 832.627 us; speedup vs baseline: 1.6576x; 1.6258x over previous
//
#include <hip/hip_runtime.h>
#include <cstdint>

#define KU 256
#define NBASK 64
#define MBS 20
#define BITEMS 1280
#define HD 256
#define G3 768
#define TT 64

typedef short v8s __attribute__((ext_vector_type(8)));
typedef float v4f __attribute__((ext_vector_type(4)));
typedef unsigned short v4us __attribute__((ext_vector_type(4)));
typedef unsigned int v4u __attribute__((ext_vector_type(4)));

__device__ __forceinline__ unsigned short f2b(float f){
  uint32_t u = __float_as_uint(f);
  u += 0x7FFFu + ((u >> 16) & 1u);
  return (unsigned short)(u >> 16);
}
__device__ __forceinline__ float b2f(unsigned short s){
  return __uint_as_float(((uint32_t)s) << 16);
}
__device__ __forceinline__ unsigned int packf(float x){
  unsigned short hi = f2b(x);
  unsigned short lo = f2b(x - b2f(hi));
  return ((unsigned int)hi << 16) | lo;
}
__device__ __forceinline__ float unpackf(unsigned int v){
  return b2f((unsigned short)(v >> 16)) + b2f((unsigned short)(v & 0xffffu));
}

// ---------------- weight conversion: fp32 -> bf16 hi + residual lo ---------
__global__ __launch_bounds__(1024) void k_convert(
    const float* __restrict__ wih, const float* __restrict__ whh,
    unsigned short* __restrict__ wih1hi, unsigned short* __restrict__ wih1lo,
    unsigned short* __restrict__ wih2hi, unsigned short* __restrict__ wih2lo,
    unsigned short* __restrict__ whh1hi, unsigned short* __restrict__ whh1lo,
    unsigned short* __restrict__ whh2hi, unsigned short* __restrict__ whh2lo)
{
  int idx = blockIdx.x * 1024 + threadIdx.x;     // 0..196607
  int which = blockIdx.y;
  float v;
  if (which == 0)      v = wih[idx];
  else if (which == 1) v = wih[196608 + idx];
  else if (which == 2) v = whh[idx];
  else                 v = whh[196608 + idx];
  unsigned short hi = f2b(v);
  unsigned short lo = f2b(v - b2f(hi));
  if (which == 0)      { wih1hi[idx] = hi; wih1lo[idx] = lo; }
  else if (which == 1) { wih2hi[idx] = hi; wih2lo[idx] = lo; }
  else if (which == 2) { whh1hi[idx] = hi; whh1lo[idx] = lo; }
  else                 { whh2hi[idx] = hi; whh2lo[idx] = lo; }
}

// ---------------- flag init ------------------------------------------------
__global__ void k_zero(int* flags){
  if (threadIdx.x < 32) flags[threadIdx.x] = 0;
}

// ---------------- per-user basket ordering (stable: valid first) -----------
__global__ __launch_bounds__(64) void k_order(
    const float* __restrict__ prob, const int* __restrict__ seq,
    int* __restrict__ order, int* __restrict__ lengths)
{
  int k = blockIdx.x, j = threadIdx.x;           // j = basket
  int base = k * BITEMS + j * MBS;
  float mx = 0.f;
  #pragma unroll
  for (int m = 0; m < MBS; m++) {
    int it = seq[base + m];
    float p = (it >= 0) ? prob[base + m] : 0.f;
    mx = fmaxf(mx, p);
  }
  bool valid = mx > 0.f;
  unsigned long long bal = __ballot(valid);
  int len = __popcll(bal);
  unsigned long long below = bal & ((1ull << j) - 1ull);
  int pos = valid ? __popcll(below) : (len + (j - __popcll(below)));
  order[k * NBASK + j] = pos;
  if (j == 0) lengths[k] = (len > 0) ? len : 1;
}

// ---------------- basket pooling -> ordered x (bf16 hi+lo) -----------------
__global__ __launch_bounds__(256) void k_basket(
    const float* __restrict__ prob, const int* __restrict__ seq,
    const float* __restrict__ table, const int* __restrict__ order,
    unsigned short* __restrict__ xbhi, unsigned short* __restrict__ xblo)
{
  int j = blockIdx.x, k = blockIdx.y;
  int h = threadIdx.x;
  int base = k * BITEMS + j * MBS;
  float acc = 0.f, sp = 0.f;
  #pragma unroll
  for (int m = 0; m < MBS; m++) {
    int it = seq[base + m];
    if (it >= 0) {
      float p = prob[base + m];
      sp += p;
      acc += p * table[(size_t)(it + 1) * HD + h];
    }
  }
  float val = acc / (sp + 1e-10f);
  int dest = order[k * NBASK + j];
  unsigned short hi = f2b(val);
  size_t o = ((size_t)k * NBASK + dest) * HD + h;
  xbhi[o] = hi;
  xblo[o] = f2b(val - b2f(hi));
}

// ---------------- 3-product split-bf16 GEMM: Y = X @ W^T + bias ------------
__global__ __launch_bounds__(256) void k_gemm3(
    const unsigned short* __restrict__ Xhi, const unsigned short* __restrict__ Xlo,
    const unsigned short* __restrict__ Whi, const unsigned short* __restrict__ Wlo,
    const float* __restrict__ bias, float* __restrict__ Y)
{
  int nblk = blockIdx.x;              // 0..11
  int mblk = blockIdx.y;              // 0..255
  int wv = threadIdx.x >> 6;
  int l = threadIdx.x & 63;
  int r = l & 15, g = l >> 4;
  int mbase = mblk * 64 + wv * 16;
  int nbase = nblk * 64;
  v4f acc[4];
  #pragma unroll
  for (int c = 0; c < 4; c++) {
    float bn = bias[nbase + c * 16 + r];
    acc[c] = (v4f){bn, bn, bn, bn};
  }
  const unsigned short* xh = Xhi + (size_t)(mbase + r) * HD;
  const unsigned short* xl = Xlo + (size_t)(mbase + r) * HD;
  #pragma unroll
  for (int k0 = 0; k0 < HD; k0 += 32) {
    v8s ahi = *(const v8s*)(xh + k0 + g * 8);
    v8s alo = *(const v8s*)(xl + k0 + g * 8);
    #pragma unroll
    for (int c = 0; c < 4; c++) {
      size_t wo = (size_t)(nbase + c * 16 + r) * HD + k0 + g * 8;
      v8s bhi = *(const v8s*)(Whi + wo);
      v8s blo = *(const v8s*)(Wlo + wo);
      acc[c] = __builtin_amdgcn_mfma_f32_16x16x32_bf16(ahi, bhi, acc[c], 0, 0, 0);
      acc[c] = __builtin_amdgcn_mfma_f32_16x16x32_bf16(alo, bhi, acc[c], 0, 0, 0);
      acc[c] = __builtin_amdgcn_mfma_f32_16x16x32_bf16(ahi, blo, acc[c], 0, 0, 0);
    }
  }
  #pragma unroll
  for (int c = 0; c < 4; c++) {
    int n = nbase + c * 16 + r;
    int mrow = mbase + g * 4;
    #pragma unroll
    for (int i = 0; i < 4; i++)
      Y[(size_t)(mrow + i) * G3 + n] = acc[c][i];
  }
}

// ---------------- shared MFMA phase (identical for all 3 stages) -----------
// gh rows {j, 256+j, 512+j} = A(h in LDS, 16 users) x B(streamed W rows + nlo)
__device__ __forceinline__ void mfma_phase(
    const unsigned short* __restrict__ w0, const unsigned short* __restrict__ w1,
    const unsigned short* __restrict__ w2,
    const unsigned short (*h_hi)[256], const unsigned short (*h_lo)[256],
    const unsigned short* nlo_s, int r, int g, int j,
    v4f& a0, v4f& a1, v4f& a2)
{
  v8s cw0[3], cw1[3], cw2[3];
  #pragma unroll
  for (int p = 0; p < 3; p++) {
    cw0[p] = *(const v8s*)(w0 + p * 32);
    cw1[p] = *(const v8s*)(w1 + p * 32);
    cw2[p] = *(const v8s*)(w2 + p * 32);
  }
  #pragma unroll
  for (int kk = 0; kk < 8; kk++) {
    int buf = kk % 3;                          // static after unroll
    int slotA = ((kk * 4 + g) ^ (r & 7)) * 8;
    v8s ahi = *(const v8s*)&h_hi[r][slotA];
    v8s alo = *(const v8s*)&h_lo[r][slotA];
    v8s nl  = *(const v8s*)&nlo_s[j * 256 + slotA];
    v8s u0 = cw0[buf], u1 = cw1[buf], u2 = cw2[buf];
    if (kk + 3 < 8) {
      cw0[buf] = *(const v8s*)(w0 + (kk + 3) * 32);
      cw1[buf] = *(const v8s*)(w1 + (kk + 3) * 32);
      cw2[buf] = *(const v8s*)(w2 + (kk + 3) * 32);
    }
    a0 = __builtin_amdgcn_mfma_f32_16x16x32_bf16(ahi, u0, a0, 0, 0, 0);
    a0 = __builtin_amdgcn_mfma_f32_16x16x32_bf16(alo, u0, a0, 0, 0, 0);
    a1 = __builtin_amdgcn_mfma_f32_16x16x32_bf16(ahi, u1, a1, 0, 0, 0);
    a1 = __builtin_amdgcn_mfma_f32_16x16x32_bf16(alo, u1, a1, 0, 0, 0);
    a2 = __builtin_amdgcn_mfma_f32_16x16x32_bf16(ahi, u2, a2, 0, 0, 0);
    a2 = __builtin_amdgcn_mfma_f32_16x16x32_bf16(alo, u2, a2, 0, 0, 0);
    a2 = __builtin_amdgcn_mfma_f32_16x16x32_bf16(ahi, nl, a2, 0, 0, 0);
  }
}

// ---------------- 3-stage pipelined GRU (48 blocks x 1024) ------------------
// role 0 (blocks 0-15):  layer-1 recurrence; publishes h1(t) packed u32.
// role 1 (blocks 16-31): gi2(t) = h1(t) @ wih2^T + bih2; overwrites gi slot t
//                        (race-free: A consumed gi1(t) before posting aflag).
// role 2 (blocks 32-47): layer-2 recurrence on gi2 stream; writes out.
// Handoff: data stores -> __syncthreads -> tid0 {__threadfence, release flag};
// consumer tid0 acquire-spins, __syncthreads, then block reads. Replay-safe:
// values are deterministic, flags re-zeroed by k_zero each call.
__global__ __launch_bounds__(1024) void k_pipeline(
    const unsigned short* __restrict__ whh1hi, const unsigned short* __restrict__ whh1lo,
    const unsigned short* __restrict__ wih2hi, const unsigned short* __restrict__ wih2lo,
    const unsigned short* __restrict__ whh2hi, const unsigned short* __restrict__ whh2lo,
    float* __restrict__ gi, unsigned int* __restrict__ h1pk,
    const float* __restrict__ bhh1, const float* __restrict__ bih2,
    const float* __restrict__ bhh2,
    const int* __restrict__ lengths, float* __restrict__ out, int* flags)
{
  __shared__ unsigned short h_hi[16][256], h_lo[16][256];
  __shared__ unsigned short nlo_s[65536];      // n-gate w-lo, swizzled (128 KB)
  int tid = threadIdx.x;
  int l = tid & 63, r = l & 15, g = l >> 4;
  int swv = __builtin_amdgcn_readfirstlane(tid >> 6);
  int role = blockIdx.x >> 4, b = blockIdx.x & 15;
  int ub = b * 16;
  int j = swv * 16 + r;
  int* aflag = flags;
  int* gflag = flags + 16;

  const unsigned short* whi_g = (role == 0) ? whh1hi : (role == 1) ? wih2hi : whh2hi;
  const unsigned short* wlo_g = (role == 0) ? whh1lo : (role == 1) ? wih2lo : whh2lo;

  for (int idx = tid; idx < 4096; idx += 1024) {
    ((unsigned short*)h_hi)[idx] = 0;
    ((unsigned short*)h_lo)[idx] = 0;
  }
  const unsigned short* wlo_n = wlo_g + 2 * 65536;
  for (int idx = tid; idx < 65536; idx += 1024) {
    int row = idx >> 8, col = idx & 255;
    int slot = (col >> 3) ^ (row & 7);
    nlo_s[row * 256 + slot * 8 + (col & 7)] = wlo_n[idx];
  }
  const unsigned short* w0 = whi_g + (size_t)j * 256 + g * 8;
  const unsigned short* w1 = w0 + 65536;
  const unsigned short* w2 = w0 + 131072;
  __syncthreads();

  if (role == 0) {
    // ================= stage A: layer-1 recurrence =================
    float b_r = bhh1[j], b_z = bhh1[256 + j], b_n = bhh1[512 + j];
    const float* gp[4];
    #pragma unroll
    for (int i = 0; i < 4; i++)
      gp[i] = gi + (size_t)(ub + g * 4 + i) * TT * G3 + j;
    float hold[4] = {0.f, 0.f, 0.f, 0.f};
    for (int t = 0; t < TT; t++) {
      float gir[4], giz[4], gin[4];
      #pragma unroll
      for (int i = 0; i < 4; i++) {
        gir[i] = gp[i][0]; giz[i] = gp[i][256]; gin[i] = gp[i][512];
        gp[i] += G3;
      }
      v4f a0 = {0.f,0.f,0.f,0.f}, a1 = {0.f,0.f,0.f,0.f}, a2 = {0.f,0.f,0.f,0.f};
      mfma_phase(w0, w1, w2, h_hi, h_lo, nlo_s, r, g, j, a0, a1, a2);
      __syncthreads();
      #pragma unroll
      for (int i = 0; i < 4; i++) {
        float hr = a0[i] + b_r, hz = a1[i] + b_z, hn = a2[i] + b_n;
        float rr = 1.f / (1.f + __expf(-(gir[i] + hr)));
        float zz = 1.f / (1.f + __expf(-(giz[i] + hz)));
        float e  = __expf(2.f * (gin[i] + rr * hn));
        float nn = 1.f - 2.f / (e + 1.f);
        float hnew = (1.f - zz) * nn + zz * hold[i];
        hold[i] = hnew;
        unsigned short h_  = f2b(hnew);
        unsigned short lo_ = f2b(hnew - b2f(h_));
        int u = g * 4 + i;
        int pos = (((j >> 3) ^ (u & 7)) << 3) + (j & 7);
        h_hi[u][pos] = h_;
        h_lo[u][pos] = lo_;
        h1pk[((size_t)(ub + u) * TT + t) * HD + j] = ((unsigned int)h_ << 16) | lo_;
      }
      __syncthreads();
      if (tid == 0) {
        __threadfence();
        __hip_atomic_store(&aflag[b], t + 1, __ATOMIC_RELEASE, __HIP_MEMORY_SCOPE_AGENT);
      }
    }
  } else if (role == 1) {
    // ================= stage G: gi2(t) = h1(t) @ wih2^T + bih2 =====
    float b_r = bih2[j], b_z = bih2[256 + j], b_n = bih2[512 + j];
    int uu = tid >> 6, q4 = tid & 63, j0 = q4 * 4;
    int slotW = (((j0 >> 3) ^ (uu & 7)) << 3) + (j0 & 7);
    unsigned int* gi_u = (unsigned int*)gi;
    for (int t = 0; t < TT; t++) {
      if (tid == 0)
        while (__hip_atomic_load(&aflag[b], __ATOMIC_ACQUIRE, __HIP_MEMORY_SCOPE_AGENT) < t + 1)
          __builtin_amdgcn_s_sleep(8);
      __syncthreads();
      v4u pk = *(const v4u*)(h1pk + ((size_t)(ub + uu) * TT + t) * HD + j0);
      v4us hv, lv;
      #pragma unroll
      for (int i = 0; i < 4; i++) {
        hv[i] = (unsigned short)(pk[i] >> 16);
        lv[i] = (unsigned short)(pk[i] & 0xffffu);
      }
      *(v4us*)&h_hi[uu][slotW] = hv;
      *(v4us*)&h_lo[uu][slotW] = lv;
      __syncthreads();
      v4f a0 = {b_r, b_r, b_r, b_r}, a1 = {b_z, b_z, b_z, b_z}, a2 = {b_n, b_n, b_n, b_n};
      mfma_phase(w0, w1, w2, h_hi, h_lo, nlo_s, r, g, j, a0, a1, a2);
      #pragma unroll
      for (int i = 0; i < 4; i++) {
        int u2 = g * 4 + i;
        size_t base = ((size_t)(ub + u2) * TT + t) * G3;
        gi_u[base + j]       = packf(a0[i]);
        gi_u[base + 256 + j] = packf(a1[i]);
        gi_u[base + 512 + j] = packf(a2[i]);
      }
      __syncthreads();
      if (tid == 0) {
        __threadfence();
        __hip_atomic_store(&gflag[b], t + 1, __ATOMIC_RELEASE, __HIP_MEMORY_SCOPE_AGENT);
      }
    }
  } else {
    // ================= stage B: layer-2 recurrence =================
    float b_r = bhh2[j], b_z = bhh2[256 + j], b_n = bhh2[512 + j];
    const unsigned int* gp[4];
    int lenr[4];
    #pragma unroll
    for (int i = 0; i < 4; i++) {
      gp[i] = (const unsigned int*)gi + (size_t)(ub + g * 4 + i) * TT * G3 + j;
      lenr[i] = lengths[ub + g * 4 + i];
    }
    float hold[4] = {0.f, 0.f, 0.f, 0.f};
    for (int t = 0; t < TT; t++) {
      if (tid == 0)
        while (__hip_atomic_load(&gflag[b], __ATOMIC_ACQUIRE, __HIP_MEMORY_SCOPE_AGENT) < t + 1)
          __builtin_amdgcn_s_sleep(8);
      __syncthreads();
      unsigned int vr[4], vz[4], vn[4];
      #pragma unroll
      for (int i = 0; i < 4; i++) {
        vr[i] = gp[i][0]; vz[i] = gp[i][256]; vn[i] = gp[i][512];
        gp[i] += G3;
      }
      v4f a0 = {0.f,0.f,0.f,0.f}, a1 = {0.f,0.f,0.f,0.f}, a2 = {0.f,0.f,0.f,0.f};
      mfma_phase(w0, w1, w2, h_hi, h_lo, nlo_s, r, g, j, a0, a1, a2);
      __syncthreads();
      #pragma unroll
      for (int i = 0; i < 4; i++) {
        float hr = a0[i] + b_r, hz = a1[i] + b_z, hn = a2[i] + b_n;
        float rr = 1.f / (1.f + __expf(-(unpackf(vr[i]) + hr)));
        float zz = 1.f / (1.f + __expf(-(unpackf(vz[i]) + hz)));
        float e  = __expf(2.f * (unpackf(vn[i]) + rr * hn));
        float nn = 1.f - 2.f / (e + 1.f);
        float hnew = (1.f - zz) * nn + zz * hold[i];
        hold[i] = hnew;
        unsigned short h_  = f2b(hnew);
        unsigned short lo_ = f2b(hnew - b2f(h_));
        int u = g * 4 + i;
        int pos = (((j >> 3) ^ (u & 7)) << 3) + (j & 7);
        h_hi[u][pos] = h_;
        h_lo[u][pos] = lo_;
        if (t == lenr[i] - 1)
          out[(size_t)(ub + u) * HD + j] = hnew;
      }
      __syncthreads();
    }
  }
}

extern "C" void kernel_launch(void* const* d_in, const int* in_sizes, int n_in,
                              void* d_out, int out_size, void* d_ws, size_t ws_size,
                              hipStream_t stream) {
  const float* prob  = (const float*)d_in[0];
  const int*   seq   = (const int*)d_in[1];
  // d_in[2] = uid (unused by the reference output)
  const float* table = (const float*)d_in[3];
  const float* wih   = (const float*)d_in[4];
  const float* whh   = (const float*)d_in[5];
  const float* bih   = (const float*)d_in[6];
  const float* bhh   = (const float*)d_in[7];
  float* out = (float*)d_out;

  char* ws = (char*)d_ws;
  float* gi            = (float*)ws;                          // 48 MB: gi1, then gi2 overlay
  unsigned short* xbhi = (unsigned short*)(ws + 50331648);    // 8 MB
  unsigned short* xblo = (unsigned short*)(ws + 58720256);    // 8 MB
  unsigned int* h1pk   = (unsigned int*)xbhi;  // overlay: xb dead after gemm1 (16 MiB exact)
  char* wsw = ws + 67108864;
  const size_t WSZ = 393216;                                  // 768*256*2 B
  unsigned short* wih1hi = (unsigned short*)(wsw + 0 * WSZ);
  unsigned short* wih1lo = (unsigned short*)(wsw + 1 * WSZ);
  unsigned short* wih2hi = (unsigned short*)(wsw + 2 * WSZ);
  unsigned short* wih2lo = (unsigned short*)(wsw + 3 * WSZ);
  unsigned short* whh1hi = (unsigned short*)(wsw + 4 * WSZ);
  unsigned short* whh1lo = (unsigned short*)(wsw + 5 * WSZ);
  unsigned short* whh2hi = (unsigned short*)(wsw + 6 * WSZ);
  unsigned short* whh2lo = (unsigned short*)(wsw + 7 * WSZ);
  int* order   = (int*)(wsw + 8 * WSZ);
  int* lengths = order + KU * NBASK;
  int* flags   = lengths + KU;

  k_zero<<<1, 64, 0, stream>>>(flags);
  k_convert<<<dim3(192, 4), 1024, 0, stream>>>(wih, whh,
      wih1hi, wih1lo, wih2hi, wih2lo, whh1hi, whh1lo, whh2hi, whh2lo);
  k_order<<<dim3(KU), 64, 0, stream>>>(prob, seq, order, lengths);
  k_basket<<<dim3(NBASK, KU), 256, 0, stream>>>(prob, seq, table, order, xbhi, xblo);
  // gi1 = x @ wih1^T + bih1  (consumes xb; xb region then becomes h1pk)
  k_gemm3<<<dim3(12, 256), 256, 0, stream>>>(xbhi, xblo, wih1hi, wih1lo, bih, gi);
  // pipelined recur1 -> gi2 -> recur2 (48 blocks, 3 stages of 16)
  k_pipeline<<<dim3(48), 1024, 0, stream>>>(
      whh1hi, whh1lo, wih2hi, wih2lo, whh2hi, whh2lo,
      gi, h1pk, bhh, bih + G3, bhh + G3, lengths, out, flags);
}

// Round 9
// 712.349 us; speedup vs baseline: 1.9374x; 1.1688x over previous
//
#include <hip/hip_runtime.h>
#include <cstdint>

#define KU 256
#define NBASK 64
#define MBS 20
#define BITEMS 1280
#define HD 256
#define G3 768
#define TT 64

typedef short v8s __attribute__((ext_vector_type(8)));
typedef float v4f __attribute__((ext_vector_type(4)));
typedef unsigned short v4us __attribute__((ext_vector_type(4)));
typedef unsigned int v4u __attribute__((ext_vector_type(4)));

__device__ __forceinline__ unsigned short f2b(float f){
  uint32_t u = __float_as_uint(f);
  u += 0x7FFFu + ((u >> 16) & 1u);
  return (unsigned short)(u >> 16);
}
__device__ __forceinline__ float b2f(unsigned short s){
  return __uint_as_float(((uint32_t)s) << 16);
}
__device__ __forceinline__ unsigned int packf(float x){
  unsigned short hi = f2b(x);
  unsigned short lo = f2b(x - b2f(hi));
  return ((unsigned int)hi << 16) | lo;
}
__device__ __forceinline__ float unpackf(unsigned int v){
  return b2f((unsigned short)(v >> 16)) + b2f((unsigned short)(v & 0xffffu));
}
__device__ __forceinline__ void waitflag(int* f, int v){
  while (__hip_atomic_load(f, __ATOMIC_ACQUIRE, __HIP_MEMORY_SCOPE_AGENT) < v)
    __builtin_amdgcn_s_sleep(2);
}

// ---------------- weight conversion: fp32 -> bf16 hi + residual lo ---------
__global__ __launch_bounds__(1024) void k_convert(
    const float* __restrict__ wih, const float* __restrict__ whh,
    unsigned short* __restrict__ wih1hi, unsigned short* __restrict__ wih1lo,
    unsigned short* __restrict__ wih2hi, unsigned short* __restrict__ wih2lo,
    unsigned short* __restrict__ whh1hi, unsigned short* __restrict__ whh1lo,
    unsigned short* __restrict__ whh2hi, unsigned short* __restrict__ whh2lo)
{
  int idx = blockIdx.x * 1024 + threadIdx.x;     // 0..196607
  int which = blockIdx.y;
  float v;
  if (which == 0)      v = wih[idx];
  else if (which == 1) v = wih[196608 + idx];
  else if (which == 2) v = whh[idx];
  else                 v = whh[196608 + idx];
  unsigned short hi = f2b(v);
  unsigned short lo = f2b(v - b2f(hi));
  if (which == 0)      { wih1hi[idx] = hi; wih1lo[idx] = lo; }
  else if (which == 1) { wih2hi[idx] = hi; wih2lo[idx] = lo; }
  else if (which == 2) { whh1hi[idx] = hi; whh1lo[idx] = lo; }
  else                 { whh2hi[idx] = hi; whh2lo[idx] = lo; }
}

// ---------------- flag init ------------------------------------------------
__global__ void k_zero(int* flags){
  if (threadIdx.x < 96) flags[threadIdx.x] = 0;
}

// ---------------- per-user basket ordering (stable: valid first) -----------
__global__ __launch_bounds__(64) void k_order(
    const float* __restrict__ prob, const int* __restrict__ seq,
    int* __restrict__ order, int* __restrict__ lengths)
{
  int k = blockIdx.x, j = threadIdx.x;           // j = basket
  int base = k * BITEMS + j * MBS;
  float mx = 0.f;
  #pragma unroll
  for (int m = 0; m < MBS; m++) {
    int it = seq[base + m];
    float p = (it >= 0) ? prob[base + m] : 0.f;
    mx = fmaxf(mx, p);
  }
  bool valid = mx > 0.f;
  unsigned long long bal = __ballot(valid);
  int len = __popcll(bal);
  unsigned long long below = bal & ((1ull << j) - 1ull);
  int pos = valid ? __popcll(below) : (len + (j - __popcll(below)));
  order[k * NBASK + j] = pos;
  if (j == 0) lengths[k] = (len > 0) ? len : 1;
}

// ---------------- basket pooling -> ordered x (bf16 hi+lo) -----------------
__global__ __launch_bounds__(256) void k_basket(
    const float* __restrict__ prob, const int* __restrict__ seq,
    const float* __restrict__ table, const int* __restrict__ order,
    unsigned short* __restrict__ xbhi, unsigned short* __restrict__ xblo)
{
  int j = blockIdx.x, k = blockIdx.y;
  int h = threadIdx.x;
  int base = k * BITEMS + j * MBS;
  float acc = 0.f, sp = 0.f;
  #pragma unroll
  for (int m = 0; m < MBS; m++) {
    int it = seq[base + m];
    if (it >= 0) {
      float p = prob[base + m];
      sp += p;
      acc += p * table[(size_t)(it + 1) * HD + h];
    }
  }
  float val = acc / (sp + 1e-10f);
  int dest = order[k * NBASK + j];
  unsigned short hi = f2b(val);
  size_t o = ((size_t)k * NBASK + dest) * HD + h;
  xbhi[o] = hi;
  xblo[o] = f2b(val - b2f(hi));
}

// ---------------- 3-product split-bf16 GEMM: Y = X @ W^T + bias ------------
__global__ __launch_bounds__(256) void k_gemm3(
    const unsigned short* __restrict__ Xhi, const unsigned short* __restrict__ Xlo,
    const unsigned short* __restrict__ Whi, const unsigned short* __restrict__ Wlo,
    const float* __restrict__ bias, float* __restrict__ Y)
{
  int nblk = blockIdx.x;              // 0..11
  int mblk = blockIdx.y;              // 0..255
  int wv = threadIdx.x >> 6;
  int l = threadIdx.x & 63;
  int r = l & 15, g = l >> 4;
  int mbase = mblk * 64 + wv * 16;
  int nbase = nblk * 64;
  v4f acc[4];
  #pragma unroll
  for (int c = 0; c < 4; c++) {
    float bn = bias[nbase + c * 16 + r];
    acc[c] = (v4f){bn, bn, bn, bn};
  }
  const unsigned short* xh = Xhi + (size_t)(mbase + r) * HD;
  const unsigned short* xl = Xlo + (size_t)(mbase + r) * HD;
  #pragma unroll
  for (int k0 = 0; k0 < HD; k0 += 32) {
    v8s ahi = *(const v8s*)(xh + k0 + g * 8);
    v8s alo = *(const v8s*)(xl + k0 + g * 8);
    #pragma unroll
    for (int c = 0; c < 4; c++) {
      size_t wo = (size_t)(nbase + c * 16 + r) * HD + k0 + g * 8;
      v8s bhi = *(const v8s*)(Whi + wo);
      v8s blo = *(const v8s*)(Wlo + wo);
      acc[c] = __builtin_amdgcn_mfma_f32_16x16x32_bf16(ahi, bhi, acc[c], 0, 0, 0);
      acc[c] = __builtin_amdgcn_mfma_f32_16x16x32_bf16(alo, bhi, acc[c], 0, 0, 0);
      acc[c] = __builtin_amdgcn_mfma_f32_16x16x32_bf16(ahi, blo, acc[c], 0, 0, 0);
    }
  }
  #pragma unroll
  for (int c = 0; c < 4; c++) {
    int n = nbase + c * 16 + r;
    int mrow = mbase + g * 4;
    #pragma unroll
    for (int i = 0; i < 4; i++)
      Y[(size_t)(mrow + i) * G3 + n] = acc[c][i];
  }
}

// ---------------- MFMA quad (4 K-slices, rolling depth-3 weight stream) ----
__device__ __forceinline__ void wprologue(
    const unsigned short* w0, const unsigned short* w1, const unsigned short* w2,
    int half4, v8s (&cw0)[3], v8s (&cw1)[3], v8s (&cw2)[3])
{
  #pragma unroll
  for (int q = 0; q < 3; q++) {
    int p = (half4 + q) & 7;
    cw0[q] = *(const v8s*)(w0 + p * 32);
    cw1[q] = *(const v8s*)(w1 + p * 32);
    cw2[q] = *(const v8s*)(w2 + p * 32);
  }
}
template<int K0>
__device__ __forceinline__ void mfma_quad(
    const unsigned short* __restrict__ w0, const unsigned short* __restrict__ w1,
    const unsigned short* __restrict__ w2,
    const unsigned short (*h_hi)[256], const unsigned short (*h_lo)[256],
    const unsigned short* __restrict__ nlo_s, int r, int g, int jloc, int half4,
    v8s (&cw0)[3], v8s (&cw1)[3], v8s (&cw2)[3],
    v4f& a0, v4f& a1, v4f& a2)
{
  #pragma unroll
  for (int q = 0; q < 4; q++) {
    int kidx = K0 + q;
    int buf = kidx % 3;                          // static after unroll
    int p = (half4 + kidx) & 7;
    int slotA = ((p * 4 + g) ^ (r & 7)) * 8;
    v8s ahi = *(const v8s*)&h_hi[r][slotA];
    v8s alo = *(const v8s*)&h_lo[r][slotA];
    v8s nl  = *(const v8s*)&nlo_s[jloc * 256 + slotA];
    v8s u0 = cw0[buf], u1 = cw1[buf], u2 = cw2[buf];
    if (kidx + 3 < 8) {
      int p3 = (half4 + kidx + 3) & 7;
      cw0[buf] = *(const v8s*)(w0 + p3 * 32);
      cw1[buf] = *(const v8s*)(w1 + p3 * 32);
      cw2[buf] = *(const v8s*)(w2 + p3 * 32);
    }
    a0 = __builtin_amdgcn_mfma_f32_16x16x32_bf16(ahi, u0, a0, 0, 0, 0);
    a0 = __builtin_amdgcn_mfma_f32_16x16x32_bf16(alo, u0, a0, 0, 0, 0);
    a1 = __builtin_amdgcn_mfma_f32_16x16x32_bf16(ahi, u1, a1, 0, 0, 0);
    a1 = __builtin_amdgcn_mfma_f32_16x16x32_bf16(alo, u1, a1, 0, 0, 0);
    a2 = __builtin_amdgcn_mfma_f32_16x16x32_bf16(ahi, u2, a2, 0, 0, 0);
    a2 = __builtin_amdgcn_mfma_f32_16x16x32_bf16(alo, u2, a2, 0, 0, 0);
    a2 = __builtin_amdgcn_mfma_f32_16x16x32_bf16(ahi, nl, a2, 0, 0, 0);
  }
}

// ---------------- j-split 3-stage pipelined GRU (96 blocks x 512) ----------
// role = bx>>5 (0=recur1, 1=gi2-GEMM, 2=recur2); sub = bx&31; half = sub>>4;
// b = sub&15 (user group). Sibling/stage partners are 16/32 apart -> same XCD.
// Each block owns 128 gate-columns (j = half*128 + swv*16 + r). Per step:
// own-half K MFMAs run BEFORE the sibling flag poll (hides exchange latency).
// A-siblings exchange h1 via t-indexed h1pk; B-siblings via single h2x buffer
// (safe: sibling's next write is flag-ordered after my read). 3 barriers/step.
__global__ __launch_bounds__(512) void k_pipe(
    const unsigned short* __restrict__ whh1hi, const unsigned short* __restrict__ whh1lo,
    const unsigned short* __restrict__ wih2hi, const unsigned short* __restrict__ wih2lo,
    const unsigned short* __restrict__ whh2hi, const unsigned short* __restrict__ whh2lo,
    float* __restrict__ gi, unsigned int* __restrict__ h1pk, unsigned int* __restrict__ h2x,
    const float* __restrict__ bhh1, const float* __restrict__ bih2,
    const float* __restrict__ bhh2,
    const int* __restrict__ lengths, float* __restrict__ out, int* flags)
{
  __shared__ unsigned short h_hi[16][256], h_lo[16][256];
  __shared__ unsigned short nlo_s[40960];   // 64KB used (+16KB pad -> 1 block/CU)
  int tid = threadIdx.x;
  int l = tid & 63, r = l & 15, g = l >> 4;
  int swv = __builtin_amdgcn_readfirstlane(tid >> 6);
  int bx = blockIdx.x;
  int role = bx >> 5, sub = bx & 31, half = sub >> 4, b = sub & 15;
  int half4 = half * 4;
  int ub = b * 16;
  int jloc = swv * 16 + r, j = half * 128 + jloc;
  int* aflag = flags, *gflag = flags + 32, *bflag = flags + 64;
  int myf = sub, sibf = sub ^ 16;

  const unsigned short* whi_g = (role == 0) ? whh1hi : (role == 1) ? wih2hi : whh2hi;
  const unsigned short* wlo_g = (role == 0) ? whh1lo : (role == 1) ? wih2lo : whh2lo;
  const float* bb_ = (role == 0) ? bhh1 : (role == 1) ? bih2 : bhh2;

  for (int idx = tid; idx < 4096; idx += 512) {
    ((unsigned short*)h_hi)[idx] = 0;
    ((unsigned short*)h_lo)[idx] = 0;
  }
  // stage this block's n-gate lo rows (its j-half), MFMA-read swizzled
  const unsigned short* wlo_n = wlo_g + 2 * 65536 + half * 128 * 256;
  for (int idx = tid; idx < 32768; idx += 512) {
    int row = idx >> 8, col = idx & 255;
    int slot = (col >> 3) ^ (row & 7);
    nlo_s[row * 256 + slot * 8 + (col & 7)] = wlo_n[idx];
  }
  const unsigned short* w0 = whi_g + (size_t)j * 256 + g * 8;
  const unsigned short* w1 = w0 + 65536;
  const unsigned short* w2 = w0 + 131072;
  float b_r = bb_[j], b_z = bb_[256 + j], b_n = bb_[512 + j];
  int sibbase = (1 - half) * 128;
  int xu = tid >> 5;                           // exchange helper coords
  __syncthreads();

  if (role == 0) {
    // ===== stage A: layer-1 recurrence (j-half) =====
    float hold[4] = {0.f, 0.f, 0.f, 0.f};
    const float* gp[4];
    unsigned int* hq[4];
    #pragma unroll
    for (int i = 0; i < 4; i++) {
      gp[i] = gi + (size_t)(ub + g * 4 + i) * TT * G3 + j;
      hq[i] = h1pk + (size_t)(ub + g * 4 + i) * TT * HD + j;
    }
    for (int t = 0; t < TT; t++) {
      float gir[4], giz[4], gin[4];
      #pragma unroll
      for (int i = 0; i < 4; i++) {
        gir[i] = gp[i][0]; giz[i] = gp[i][256]; gin[i] = gp[i][512];
        gp[i] += G3;
      }
      v8s cw0[3], cw1[3], cw2[3];
      wprologue(w0, w1, w2, half4, cw0, cw1, cw2);
      v4f a0 = {0.f,0.f,0.f,0.f}, a1 = {0.f,0.f,0.f,0.f}, a2 = {0.f,0.f,0.f,0.f};
      mfma_quad<0>(w0, w1, w2, h_hi, h_lo, nlo_s, r, g, jloc, half4, cw0, cw1, cw2, a0, a1, a2);
      if (t > 0 && tid == 0) waitflag(&aflag[sibf], t);
      __syncthreads();
      if (t > 0) {
        int sj = sibbase + (tid & 31) * 4;
        v4u pk = *(const v4u*)&h1pk[((size_t)(ub + xu) * TT + (t - 1)) * HD + sj];
        int pos = (((sj >> 3) ^ (xu & 7)) << 3) + (sj & 7);
        v4us hv, lv;
        #pragma unroll
        for (int i = 0; i < 4; i++) { hv[i] = (unsigned short)(pk[i] >> 16); lv[i] = (unsigned short)(pk[i] & 0xffffu); }
        *(v4us*)&h_hi[xu][pos] = hv;
        *(v4us*)&h_lo[xu][pos] = lv;
      }
      __syncthreads();
      mfma_quad<4>(w0, w1, w2, h_hi, h_lo, nlo_s, r, g, jloc, half4, cw0, cw1, cw2, a0, a1, a2);
      #pragma unroll
      for (int i = 0; i < 4; i++) {
        float hr = a0[i] + b_r, hz = a1[i] + b_z, hn = a2[i] + b_n;
        float rr = 1.f / (1.f + __expf(-(gir[i] + hr)));
        float zz = 1.f / (1.f + __expf(-(giz[i] + hz)));
        float e  = __expf(2.f * (gin[i] + rr * hn));
        float nn = 1.f - 2.f / (e + 1.f);
        float hnew = (1.f - zz) * nn + zz * hold[i];
        hold[i] = hnew;
        unsigned short h_  = f2b(hnew);
        unsigned short lo_ = f2b(hnew - b2f(h_));
        int u = g * 4 + i;
        int pos = (((j >> 3) ^ (u & 7)) << 3) + (j & 7);
        h_hi[u][pos] = h_;
        h_lo[u][pos] = lo_;
        hq[i][0] = ((unsigned int)h_ << 16) | lo_;
        hq[i] += HD;
      }
      __syncthreads();
      if (tid == 0) {
        __threadfence();
        __hip_atomic_store(&aflag[myf], t + 1, __ATOMIC_RELEASE, __HIP_MEMORY_SCOPE_AGENT);
      }
    }
  } else if (role == 1) {
    // ===== stage G: gi2(t) = h1(t) @ wih2^T + bih2 (j-half rows) =====
    unsigned int* gi_u = (unsigned int*)gi;
    for (int t = 0; t < TT; t++) {
      if (tid == 0) { waitflag(&aflag[b], t + 1); waitflag(&aflag[16 + b], t + 1); }
      __syncthreads();
      {
        int c0 = (tid & 31) * 8;
        const unsigned int* src = &h1pk[((size_t)(ub + xu) * TT + t) * HD + c0];
        #pragma unroll
        for (int hf = 0; hf < 2; hf++) {
          v4u pk = *(const v4u*)(src + hf * 4);
          int sj = c0 + hf * 4;
          int pos = (((sj >> 3) ^ (xu & 7)) << 3) + (sj & 7);
          v4us hv, lv;
          #pragma unroll
          for (int i = 0; i < 4; i++) { hv[i] = (unsigned short)(pk[i] >> 16); lv[i] = (unsigned short)(pk[i] & 0xffffu); }
          *(v4us*)&h_hi[xu][pos] = hv;
          *(v4us*)&h_lo[xu][pos] = lv;
        }
      }
      __syncthreads();
      v8s cw0[3], cw1[3], cw2[3];
      wprologue(w0, w1, w2, half4, cw0, cw1, cw2);
      v4f a0 = {b_r, b_r, b_r, b_r}, a1 = {b_z, b_z, b_z, b_z}, a2 = {b_n, b_n, b_n, b_n};
      mfma_quad<0>(w0, w1, w2, h_hi, h_lo, nlo_s, r, g, jloc, half4, cw0, cw1, cw2, a0, a1, a2);
      mfma_quad<4>(w0, w1, w2, h_hi, h_lo, nlo_s, r, g, jloc, half4, cw0, cw1, cw2, a0, a1, a2);
      #pragma unroll
      for (int i = 0; i < 4; i++) {
        size_t base = ((size_t)(ub + g * 4 + i) * TT + t) * G3;
        gi_u[base + j]       = packf(a0[i]);
        gi_u[base + 256 + j] = packf(a1[i]);
        gi_u[base + 512 + j] = packf(a2[i]);
      }
      __syncthreads();
      if (tid == 0) {
        __threadfence();
        __hip_atomic_store(&gflag[myf], t + 1, __ATOMIC_RELEASE, __HIP_MEMORY_SCOPE_AGENT);
      }
    }
  } else {
    // ===== stage B: layer-2 recurrence (j-half) =====
    float hold[4] = {0.f, 0.f, 0.f, 0.f};
    const unsigned int* gq[4];
    int lenr[4];
    #pragma unroll
    for (int i = 0; i < 4; i++) {
      gq[i] = (const unsigned int*)gi + (size_t)(ub + g * 4 + i) * TT * G3 + j;
      lenr[i] = lengths[ub + g * 4 + i];
    }
    for (int t = 0; t < TT; t++) {
      v8s cw0[3], cw1[3], cw2[3];
      wprologue(w0, w1, w2, half4, cw0, cw1, cw2);
      v4f a0 = {0.f,0.f,0.f,0.f}, a1 = {0.f,0.f,0.f,0.f}, a2 = {0.f,0.f,0.f,0.f};
      mfma_quad<0>(w0, w1, w2, h_hi, h_lo, nlo_s, r, g, jloc, half4, cw0, cw1, cw2, a0, a1, a2);
      if (tid == 0) {
        waitflag(&gflag[myf], t + 1);
        if (t > 0) waitflag(&bflag[sibf], t);
      }
      __syncthreads();
      if (t > 0) {
        int sj = sibbase + (tid & 31) * 4;
        v4u pk = *(const v4u*)&h2x[(size_t)(ub + xu) * HD + sj];
        int pos = (((sj >> 3) ^ (xu & 7)) << 3) + (sj & 7);
        v4us hv, lv;
        #pragma unroll
        for (int i = 0; i < 4; i++) { hv[i] = (unsigned short)(pk[i] >> 16); lv[i] = (unsigned short)(pk[i] & 0xffffu); }
        *(v4us*)&h_hi[xu][pos] = hv;
        *(v4us*)&h_lo[xu][pos] = lv;
      }
      unsigned int vr[4], vz[4], vn[4];
      #pragma unroll
      for (int i = 0; i < 4; i++) {
        vr[i] = gq[i][0]; vz[i] = gq[i][256]; vn[i] = gq[i][512];
        gq[i] += G3;
      }
      __syncthreads();
      mfma_quad<4>(w0, w1, w2, h_hi, h_lo, nlo_s, r, g, jloc, half4, cw0, cw1, cw2, a0, a1, a2);
      #pragma unroll
      for (int i = 0; i < 4; i++) {
        float hr = a0[i] + b_r, hz = a1[i] + b_z, hn = a2[i] + b_n;
        float rr = 1.f / (1.f + __expf(-(unpackf(vr[i]) + hr)));
        float zz = 1.f / (1.f + __expf(-(unpackf(vz[i]) + hz)));
        float e  = __expf(2.f * (unpackf(vn[i]) + rr * hn));
        float nn = 1.f - 2.f / (e + 1.f);
        float hnew = (1.f - zz) * nn + zz * hold[i];
        hold[i] = hnew;
        unsigned short h_  = f2b(hnew);
        unsigned short lo_ = f2b(hnew - b2f(h_));
        int u = g * 4 + i;
        int pos = (((j >> 3) ^ (u & 7)) << 3) + (j & 7);
        h_hi[u][pos] = h_;
        h_lo[u][pos] = lo_;
        h2x[(size_t)(ub + u) * HD + j] = ((unsigned int)h_ << 16) | lo_;
        if (t == lenr[i] - 1)
          out[(size_t)(ub + u) * HD + j] = hnew;
      }
      __syncthreads();
      if (tid == 0) {
        __threadfence();
        __hip_atomic_store(&bflag[myf], t + 1, __ATOMIC_RELEASE, __HIP_MEMORY_SCOPE_AGENT);
      }
    }
  }
}

extern "C" void kernel_launch(void* const* d_in, const int* in_sizes, int n_in,
                              void* d_out, int out_size, void* d_ws, size_t ws_size,
                              hipStream_t stream) {
  const float* prob  = (const float*)d_in[0];
  const int*   seq   = (const int*)d_in[1];
  // d_in[2] = uid (unused by the reference output)
  const float* table = (const float*)d_in[3];
  const float* wih   = (const float*)d_in[4];
  const float* whh   = (const float*)d_in[5];
  const float* bih   = (const float*)d_in[6];
  const float* bhh   = (const float*)d_in[7];
  float* out = (float*)d_out;

  char* ws = (char*)d_ws;
  float* gi            = (float*)ws;                          // 48 MB: gi1, then gi2 overlay
  unsigned short* xbhi = (unsigned short*)(ws + 50331648);    // 8 MB
  unsigned short* xblo = (unsigned short*)(ws + 58720256);    // 8 MB
  unsigned int* h1pk   = (unsigned int*)xbhi;  // overlay: xb dead after gemm1 (16 MiB)
  char* wsw = ws + 67108864;
  const size_t WSZ = 393216;                                  // 768*256*2 B
  unsigned short* wih1hi = (unsigned short*)(wsw + 0 * WSZ);
  unsigned short* wih1lo = (unsigned short*)(wsw + 1 * WSZ);
  unsigned short* wih2hi = (unsigned short*)(wsw + 2 * WSZ);
  unsigned short* wih2lo = (unsigned short*)(wsw + 3 * WSZ);
  unsigned short* whh1hi = (unsigned short*)(wsw + 4 * WSZ);
  unsigned short* whh1lo = (unsigned short*)(wsw + 5 * WSZ);
  unsigned short* whh2hi = (unsigned short*)(wsw + 6 * WSZ);
  unsigned short* whh2lo = (unsigned short*)(wsw + 7 * WSZ);
  int* order   = (int*)(wsw + 8 * WSZ);
  int* lengths = order + KU * NBASK;
  int* flags   = lengths + KU;
  unsigned int* h2x = (unsigned int*)wih1hi;   // overlay: wih1 dead after gemm1 (256 KB < 384 KB)

  k_zero<<<1, 128, 0, stream>>>(flags);
  k_convert<<<dim3(192, 4), 1024, 0, stream>>>(wih, whh,
      wih1hi, wih1lo, wih2hi, wih2lo, whh1hi, whh1lo, whh2hi, whh2lo);
  k_order<<<dim3(KU), 64, 0, stream>>>(prob, seq, order, lengths);
  k_basket<<<dim3(NBASK, KU), 256, 0, stream>>>(prob, seq, table, order, xbhi, xblo);
  // gi1 = x @ wih1^T + bih1  (consumes xb and wih1; those regions then recycle)
  k_gemm3<<<dim3(12, 256), 256, 0, stream>>>(xbhi, xblo, wih1hi, wih1lo, bih, gi);
  // j-split pipelined recur1 -> gi2 -> recur2 (96 blocks, 3 roles x 16 groups x 2 halves)
  k_pipe<<<dim3(96), 512, 0, stream>>>(
      whh1hi, whh1lo, wih2hi, wih2lo, whh2hi, whh2lo,
      gi, h1pk, h2x, bhh, bih + G3, bhh + G3, lengths, out, flags);
}